// Round 13
// baseline (362.086 us; speedup 1.0000x reference)
//
#include <hip/hip_runtime.h>
#include <hip/hip_bf16.h>

#define NN 50000
#define NE 600000
#define DD 128
#define RB 64            // rows per MFMA block (4 waves x 16 rows)
#define GB ((NN + RB - 1) / RB)      // 782 MFMA blocks
#define NBE ((NE + 4095) / 4096)     // 147 edge blocks (16 edges/thread)
#define NBUCK 196                    // node buckets of 256 (node>>8)
#define SB ((NN + 1023) / 1024)      // 49 scan blocks
#define GQB3 (2 * ((NN + 31) / 32))  // 3126 gather blocks (2 planes x 1563 chunks)
#define NLO 25000                    // lo/hi neighbor split point (NN/2)

typedef __bf16 bfrag __attribute__((ext_vector_type(8)));
typedef float  ffrag __attribute__((ext_vector_type(4)));
typedef unsigned uintv4 __attribute__((ext_vector_type(4)));   // native vec for nontemporal
typedef unsigned uintv2 __attribute__((ext_vector_type(2)));

union frag_cast { uintv4 u4; unsigned u[4]; bfrag b; };

__device__ __forceinline__ float bfbits2f(unsigned v) { return __uint_as_float(v << 16); }
__device__ __forceinline__ unsigned f2bfbits(float f) {
    unsigned u = __float_as_uint(f);
    return (u + 0x7FFFu + ((u >> 16) & 1u)) >> 16;   // RNE
}

__device__ __forceinline__ float ld_in(const void* p, int idx, int f32) {
    return f32 ? ((const float*)p)[idx]
               : bfbits2f(((const unsigned short*)p)[idx]);
}

__device__ __forceinline__ void ld_edge_nt(const int* adj, int e, int i64, int& s, int& d) {
    if (i64) {
        s = __builtin_nontemporal_load(&adj[4 * e]);
        d = __builtin_nontemporal_load(&adj[4 * e + 2]);
    } else {
        s = __builtin_nontemporal_load(&adj[2 * e]);
        d = __builtin_nontemporal_load(&adj[2 * e + 1]);
    }
}

// ---------------- prep: weight transpose + sniff ----------------
__global__ void k_prep(const unsigned* __restrict__ Ww, const unsigned* __restrict__ adjw,
                       const void* __restrict__ We, const void* __restrict__ Wu,
                       unsigned short* __restrict__ WeT, unsigned short* __restrict__ WuT,
                       int* __restrict__ flags) {
    const int tid = threadIdx.x;
    if (blockIdx.x < DD) {
        __shared__ int scnt;
        if (tid == 0) scnt = 0;
        __syncthreads();
        int c = 0;
        for (int i = tid; i < 512; i += 256) {
            unsigned e = (Ww[i] >> 7) & 0xFFu;
            c += (e >= 0x60u && e <= 0x85u) ? 1 : 0;   // plausible low-half bf16?
        }
        atomicAdd(&scnt, c);
        __syncthreads();
        const int f32 = (scnt >= 256) ? 0 : 1;
        const int k = blockIdx.x;
        if (tid < DD) {
            WeT[tid * DD + k] = (unsigned short)f2bfbits(ld_in(We, k * DD + tid, f32));
        } else {
            int n = tid - DD;
            WuT[n * DD + k] = (unsigned short)f2bfbits(ld_in(Wu, k * DD + n, f32));
        }
        return;
    }
    __shared__ int cnt[2];
    if (tid < 2) cnt[tid] = 0;
    __syncthreads();
    int c0 = 0, c1 = 0;
    for (int i = tid; i < 512; i += 256) {
        unsigned e = (Ww[i] >> 7) & 0xFFu;
        c0 += (e >= 0x60u && e <= 0x85u) ? 1 : 0;
        c1 += (adjw[2 * i + 1] == 0u) ? 1 : 0;          // int64 zero high words?
    }
    atomicAdd(&cnt[0], c0);
    atomicAdd(&cnt[1], c1);
    __syncthreads();
    if (tid == 0) {
        flags[0] = (cnt[0] >= 256) ? 0 : 1;   // fp32 inputs?
        flags[1] = (cnt[1] >= 256) ? 1 : 0;   // int64 adjacency?
    }
}

// ---------------- W staging: fragment-major LDS, INVERSE permutation ----------------
__device__ __forceinline__ void stage_w(const uintv4* __restrict__ WTg, uintv4* sW, int tid) {
#pragma unroll
    for (int k = 0; k < 8; k++) {
        int d = k * 256 + tid;
        int m = d & 15, rest = d >> 4;
        int quad = rest & 3, ks = (rest >> 2) & 3, ct = rest >> 4;
        sW[d] = WTg[(ct * 16 + m) * 16 + (ks * 4 + quad)];
    }
}

// ---------------- MFMA core: A from registers, B fragment-major from LDS ----------
__device__ __forceinline__ void mfma_rows(const bfrag af[4], const bfrag* sW,
                                          int m, int quad, ffrag acc[8]) {
#pragma unroll
    for (int ks = 0; ks < 4; ks++) {
#pragma unroll
        for (int ct = 0; ct < 8; ct++) {
            bfrag bf_ = sW[((ct * 4 + ks) * 4 + quad) * 16 + m];
            acc[ct] = __builtin_amdgcn_mfma_f32_16x16x32_bf16(af[ks], bf_, acc[ct], 0, 0, 0);
        }
    }
}

// H layout between GEMMs: 2 HALF-ROW PLANES H2[plane][node][64cols] (128B/node/plane)
// -> every gather neighbor-read is ONE fully-used 128B L2 line request.
__device__ __forceinline__ void st_h2(unsigned short* __restrict__ Hout,
                                      int ct, int m, int orow, float z) {
    Hout[(size_t)(ct >> 2) * (NN * 64) + (size_t)orow * 64 + (ct & 3) * 16 + m] =
        (unsigned short)f2bfbits(z);
}

// ---------------- fused: emb GEMM (blocks < GB) || P1a bucket histogram (rest) -----
__launch_bounds__(256, 5)
__global__ void k_main1(const void* __restrict__ Xp, const unsigned short* __restrict__ WTg,
                        const void* __restrict__ Bp, unsigned short* __restrict__ Hout,
                        const int* __restrict__ flags, const int* __restrict__ adj,
                        int* __restrict__ bh1) {
    __shared__ __align__(16) unsigned short sWT[DD * DD];  // 32 KB
    const int tid = threadIdx.x;
    if (blockIdx.x >= GB) {
        int* hist = (int*)sWT;                 // reuse LDS (edge blocks never stage W)
        const int bb = blockIdx.x - GB;
        hist[tid] = 0;
        __syncthreads();
        const int i64 = flags[1];
#pragma unroll
        for (int k = 0; k < 16; k++) {
            const int e = bb * 4096 + k * 256 + tid;
            if (e < NE) {
                int s, d;
                ld_edge_nt(adj, e, i64, s, d);
                if ((unsigned)s < NN && (unsigned)d < NN) {
                    atomicAdd(&hist[s >> 8], 1);   // LDS atomic (~21/bucket avg)
                    atomicAdd(&hist[d >> 8], 1);
                }
            }
        }
        __syncthreads();
        if (tid < NBUCK) bh1[tid * NBE + bb] = hist[tid];
        return;
    }
    // -------- emb path: h0 = relu(X @ W_emb + b) -> bf16 half-row planes --------
    const int wave = tid >> 6;
    const int lane = tid & 63;
    const int f32  = flags[0];
    const int m    = lane & 15;
    const int quad = lane >> 4;
    const int rowbase = blockIdx.x * RB + wave * 16;
    const int row  = rowbase + m;
    const int rc   = (row < NN) ? row : (NN - 1);   // clamp for load; stores guarded

    stage_w((const uintv4*)WTg, (uintv4*)sWT, tid);

    bfrag af[4];
    if (f32) {
        const float4* Xf = (const float4*)Xp;
#pragma unroll
        for (int ks = 0; ks < 4; ks++) {
            const int k0 = ks * 32 + quad * 8;
            float4 a0 = Xf[rc * 32 + (k0 >> 2)];
            float4 a1 = Xf[rc * 32 + (k0 >> 2) + 1];
            frag_cast fc;
            fc.u[0] = f2bfbits(a0.x) | (f2bfbits(a0.y) << 16);
            fc.u[1] = f2bfbits(a0.z) | (f2bfbits(a0.w) << 16);
            fc.u[2] = f2bfbits(a1.x) | (f2bfbits(a1.y) << 16);
            fc.u[3] = f2bfbits(a1.z) | (f2bfbits(a1.w) << 16);
            af[ks] = fc.b;
        }
    } else {
        const uintv4* Xv = (const uintv4*)Xp;
#pragma unroll
        for (int ks = 0; ks < 4; ks++) {
            const int k0 = ks * 32 + quad * 8;
            frag_cast fc;
            fc.u4 = Xv[rc * 16 + (k0 >> 3)];
            af[ks] = fc.b;
        }
    }
    __syncthreads();

    ffrag acc[8];
#pragma unroll
    for (int i = 0; i < 8; i++) acc[i] = (ffrag)(0.0f);
    mfma_rows(af, (const bfrag*)sWT, m, quad, acc);

#pragma unroll
    for (int ct = 0; ct < 8; ct++) {
        int col = ct * 16 + m;
        float bb = ld_in(Bp, col, f32);
#pragma unroll
        for (int reg = 0; reg < 4; reg++) {
            int orow = rowbase + quad * 4 + reg;
            if (orow < NN) {
                float z = fmaxf(acc[ct][reg] + bb, 0.0f);
                st_h2(Hout, ct, m, orow, z);
            }
        }
    }
}

// ---------------- scanB: per-bucket scan across edge blocks + bucket bases ---------
__global__ void k_scanB(const int* __restrict__ bh1, int* __restrict__ bkoff,
                        int* __restrict__ bkbase) {
    __shared__ int tot[256];
    __shared__ int wps[4];
    const int t = threadIdx.x, lane = t & 63, w = t >> 6;   // 16 waves
    for (int k = w; k < NBUCK; k += 16) {
        int vals[3];                                        // ceil(147/64)=3 chunks
#pragma unroll
        for (int c = 0; c < 3; c++) {
            int idx = c * 64 + lane;
            vals[c] = (idx < NBE) ? bh1[k * NBE + idx] : 0;
        }
        int carry = 0;
#pragma unroll
        for (int c = 0; c < 3; c++) {
            int v = vals[c], x = v;
#pragma unroll
            for (int off = 1; off < 64; off <<= 1) {
                int y = __shfl_up(x, off, 64);
                if (lane >= off) x += y;
            }
            int idx = c * 64 + lane;
            if (idx < NBE) bkoff[k * NBE + idx] = carry + x - v;
            carry += __shfl(x, 63, 64);
        }
        if (lane == 0) tot[k] = carry;
    }
    if (t < 256 && t >= NBUCK) tot[t] = 0;
    __syncthreads();
    int v = 0, x = 0;
    if (t < 256) {
        v = tot[t]; x = v;
#pragma unroll
        for (int off = 1; off < 64; off <<= 1) {
            int y = __shfl_up(x, off, 64);
            if (lane >= off) x += y;
        }
        if (lane == 63) wps[w] = x;
    }
    __syncthreads();
    if (t < NBUCK) {
        int add = 0;
        for (int k = 0; k < w; k++) add += wps[k];
        bkbase[t] = x - v + add;
        if (t == NBUCK - 1) bkbase[NBUCK] = x + add;   // total endpoint count
    }
}

// ---------------- p1b: bucket-sorted record scatter (LDS cursors, no global atomics)
__launch_bounds__(256)
__global__ void k_p1b(const int* __restrict__ adj, const int* __restrict__ flags,
                      const int* __restrict__ bkbase, const int* __restrict__ bkoff,
                      unsigned* __restrict__ rec) {
    __shared__ int cur[256];
    const int tid = threadIdx.x;
    const int bb = blockIdx.x;
    if (tid < NBUCK) cur[tid] = bkbase[tid] + bkoff[tid * NBE + bb];
    __syncthreads();
    const int i64 = flags[1];
#pragma unroll
    for (int k = 0; k < 16; k++) {
        const int e = bb * 4096 + k * 256 + tid;
        if (e < NE) {
            int s, d;
            ld_edge_nt(adj, e, i64, s, d);
            if ((unsigned)s < NN && (unsigned)d < NN) {   // same predicate as P1a
                int ps = atomicAdd(&cur[s >> 8], 1);      // LDS atomic
                rec[ps] = (unsigned)s | ((unsigned)d << 16);
                int pd = atomicAdd(&cur[d >> 8], 1);
                rec[pd] = (unsigned)d | ((unsigned)s << 16);
            }
        }
    }
}

// ---------------- p2a: per-bucket degree + LO-degree histograms ----------------
__launch_bounds__(256)
__global__ void k_p2a(const unsigned* __restrict__ rec, const int* __restrict__ bkbase,
                      int* __restrict__ deg, int* __restrict__ deglo) {
    __shared__ int dh[256];
    __shared__ int dhlo[256];
    const int tid = threadIdx.x;
    const int k = blockIdx.x;
    dh[tid] = 0;
    dhlo[tid] = 0;
    __syncthreads();
    const int st = bkbase[k], en = bkbase[k + 1];
    for (int j = st + tid; j < en; j += 256) {
        unsigned r = rec[j];
        atomicAdd(&dh[r & 255], 1);                       // LDS atomic
        if ((r >> 16) < NLO) atomicAdd(&dhlo[r & 255], 1);
    }
    __syncthreads();
    const int node = k * 256 + tid;
    if (node < NN) {
        deg[node] = dh[tid];
        deglo[node] = dhlo[tid];
    }
}

// ---------------- scan1: prefix of deg + per-block 256-bin histogram --------------
__global__ void k_scan1(const int* __restrict__ deg, int* __restrict__ rows,
                        int* __restrict__ sums, int* __restrict__ bhist) {
    __shared__ int wsum[16];
    __shared__ int woff[16];
    __shared__ int hist[256];
    const int tid  = threadIdx.x;
    const int wid  = tid >> 6;
    const int lane = tid & 63;
    const int i = blockIdx.x * 1024 + tid;
    if (tid < 256) hist[tid] = 0;
    __syncthreads();
    int x = (i < NN) ? deg[i] : 0;
    if (i < NN) atomicAdd(&hist[(x < 255) ? x : 255], 1);   // LDS atomic: cheap
#pragma unroll
    for (int off = 1; off < 64; off <<= 1) {
        int y = __shfl_up(x, off, 64);
        if (lane >= off) x += y;
    }
    if (lane == 63) wsum[wid] = x;
    __syncthreads();
    if (wid == 0) {
        int s  = (lane < 16) ? wsum[lane] : 0;
        int xs = s;
#pragma unroll
        for (int off = 1; off < 16; off <<= 1) {
            int y = __shfl_up(xs, off, 64);
            if (lane >= off) xs += y;
        }
        if (lane < 16) woff[lane] = xs - s;
        if (lane == 15) sums[blockIdx.x] = xs;
    }
    __syncthreads();
    if (i < NN) rows[i + 1] = x + woff[wid];
    if (tid < 256) bhist[blockIdx.x * 256 + tid] = hist[tid];
}

// ---------------- scan2: block-sums scan + counting-sort offset tables ------------
__global__ void k_scan2(int* __restrict__ sums, int nb,
                        const int* __restrict__ bhist, int* __restrict__ boff,
                        int* __restrict__ bbase) {
    __shared__ int wps[4];
    const int t = threadIdx.x, lane = t & 63, w = t >> 6;
    if (w == 0) {
        int v = (lane < nb) ? sums[lane] : 0;
        int x = v;
        for (int off = 1; off < 64; off <<= 1) {
            int y = __shfl_up(x, off, 64);
            if (lane >= off) x += y;
        }
        if (lane < nb) sums[lane] = x - v;   // exclusive
    }
    int run = 0;
    for (int blk = 0; blk < nb; blk++) {
        int c = bhist[blk * 256 + t];
        boff[blk * 256 + t] = run;
        run += c;
    }
    int v = run, x = v;
    for (int off = 1; off < 64; off <<= 1) {
        int y = __shfl_up(x, off, 64);
        if (lane >= off) x += y;
    }
    if (lane == 63) wps[w] = x;
    __syncthreads();
    int add = 0;
    for (int k = 0; k < w; k++) add += wps[k];
    bbase[t] = x - v + add;                  // exclusive over 256 bins
}

// ---------------- scan3: finalize rows + contention-free sort scatter -------------
__global__ void k_scan3(const int* __restrict__ sums, int* __restrict__ rows,
                        const int* __restrict__ deg, const int* __restrict__ boff,
                        const int* __restrict__ bbase, int* __restrict__ order) {
    __shared__ int lh[256];
    const int tid = threadIdx.x;
    if (tid < 256) lh[tid] = 0;
    __syncthreads();
    int i = blockIdx.x * 1024 + tid;
    int d = 0, r = 0;
    if (i < NN) {
        rows[i + 1] += sums[blockIdx.x];
        if (i == 0) rows[0] = 0;
        d = deg[i];
        d = (d < 255) ? d : 255;
        r = atomicAdd(&lh[d], 1);            // LDS atomic
        order[bbase[d] + boff[blockIdx.x * 256 + d] + r] = i;  // perf hint only
    }
}

// ---------------- p2b: per-bucket NBR fill, lists SPLIT lo-first/hi-second ---------
__launch_bounds__(256)
__global__ void k_p2b(const unsigned* __restrict__ rec, const int* __restrict__ bkbase,
                      const int* __restrict__ rows, const int* __restrict__ deglo,
                      unsigned short* __restrict__ nbr) {
    __shared__ int lcur[256];
    __shared__ int hcur[256];
    const int tid = threadIdx.x;
    const int k = blockIdx.x;
    const int node = k * 256 + tid;
    const int rbase = (node < NN) ? rows[node] : 0;
    lcur[tid] = rbase;
    hcur[tid] = rbase + ((node < NN) ? deglo[node] : 0);
    __syncthreads();
    const int st = bkbase[k], en = bkbase[k + 1];
    for (int j = st + tid; j < en; j += 256) {
        unsigned r = rec[j];
        unsigned nb = r >> 16;
        int slot = (nb < NLO) ? atomicAdd(&lcur[r & 255], 1)
                              : atomicAdd(&hcur[r & 255], 1);   // LDS atomic
        nbr[slot] = (unsigned short)nb;
    }
}

__device__ __forceinline__ void accv4(float a[8], uintv4 v) {
#pragma unroll
    for (int k = 0; k < 4; k++) {
        a[2 * k]     += bfbits2f(v[k] & 0xFFFFu);
        a[2 * k + 1] += bfbits2f(v[k] >> 16);
    }
}

__device__ __forceinline__ void gath_range(const uintv4* __restrict__ Pv,
                                           const unsigned short* __restrict__ nbr,
                                           int j, int en, int l8, float a[8]) {
    for (; j + 8 <= en; j += 8) {                      // 8 line-loads in flight/group
        int n[8];
#pragma unroll
        for (int t = 0; t < 8; t++) n[t] = nbr[j + t];
        uintv4 v[8];
#pragma unroll
        for (int t = 0; t < 8; t++) v[t] = Pv[(size_t)n[t] * 8 + l8];
#pragma unroll
        for (int t = 0; t < 8; t++) accv4(a, v[t]);
    }
    for (; j < en; ++j) accv4(a, Pv[(size_t)nbr[j] * 8 + l8]);
}

// ---------------- pass L: self + lo-neighbors -> bf16 PARTIAL in XB slot ----------
// R12 counters: gather dur == FETCH/1.55 TB/s (miss-traffic-bound); implicit lo/hi
// phasing failed (FETCH unchanged). EXPLICIT phase split: this pass touches only
// neighbors < NLO -> per-XCD working set = 3.2 MB half-plane, truly L2-resident.
// Partial stored UNNORMALIZED as bf16 at XB's final location (read back by pass H).
__launch_bounds__(256)
__global__ void k_gathL(const unsigned* __restrict__ Hp, const int* __restrict__ rows,
                        const int* __restrict__ deglo,
                        const unsigned short* __restrict__ nbr,
                        const int* __restrict__ order, unsigned* __restrict__ XB32) {
    const int plane = blockIdx.x & 1;
    const int chunk = blockIdx.x >> 1;
    const int g     = threadIdx.x >> 3;
    const int l8    = threadIdx.x & 7;
    const int opos  = chunk * 32 + g;
    const int nid   = order[(opos < NN) ? opos : (NN - 1)];
    const uintv4* Pv = (const uintv4*)Hp + (size_t)plane * (NN * 8);
    const int st = rows[nid];
    const int mid = st + deglo[nid];
    uintv4 sv = Pv[(size_t)nid * 8 + l8];              // self term
    float a[8];
#pragma unroll
    for (int k = 0; k < 4; k++) {
        a[2 * k]     = bfbits2f(sv[k] & 0xFFFFu);
        a[2 * k + 1] = bfbits2f(sv[k] >> 16);
    }
    gath_range(Pv, nbr, st, mid, l8, a);               // lo neighbors only
    if (opos < NN) {
        uintv4 pk;
#pragma unroll
        for (int k = 0; k < 4; k++)
            pk[k] = f2bfbits(a[2 * k]) | (f2bfbits(a[2 * k + 1]) << 16);
        // NT store: don't let the partial stream evict the resident half-plane
        __builtin_nontemporal_store(pk, (uintv4*)XB32 + (size_t)nid * 16 + plane * 8 + l8);
    }
}

// ---------------- pass H: partial + hi-neighbors -> final XB (normalized) ---------
// Same grid mapping as pass L (chunk->XCD consistent). Working set = hi half-plane.
__launch_bounds__(256)
__global__ void k_gathH(const unsigned* __restrict__ Hp, const int* __restrict__ rows,
                        const int* __restrict__ deglo,
                        const unsigned short* __restrict__ nbr,
                        const int* __restrict__ order, unsigned* __restrict__ XB32) {
    const int plane = blockIdx.x & 1;
    const int chunk = blockIdx.x >> 1;
    const int g     = threadIdx.x >> 3;
    const int l8    = threadIdx.x & 7;
    const int opos  = chunk * 32 + g;
    const int nid   = order[(opos < NN) ? opos : (NN - 1)];
    const uintv4* Pv = (const uintv4*)Hp + (size_t)plane * (NN * 8);
    const int st = rows[nid], en = rows[nid + 1];
    const int mid = st + deglo[nid];
    uintv4 pv = *((const uintv4*)XB32 + (size_t)nid * 16 + plane * 8 + l8);  // partial
    float a[8];
#pragma unroll
    for (int k = 0; k < 4; k++) {
        a[2 * k]     = bfbits2f(pv[k] & 0xFFFFu);
        a[2 * k + 1] = bfbits2f(pv[k] >> 16);
    }
    gath_range(Pv, nbr, mid, en, l8, a);               // hi neighbors only
    const float inv = 1.0f / (float)(en - st + 1);
    if (opos < NN) {
        uintv4 pk;
#pragma unroll
        for (int k = 0; k < 4; k++)
            pk[k] = f2bfbits(a[2 * k] * inv) | (f2bfbits(a[2 * k + 1] * inv) << 16);
        __builtin_nontemporal_store(pk, (uintv4*)XB32 + (size_t)nid * 16 + plane * 8 + l8);
    }
}

// ---------------- GEMM 2: h_new = sigmoid(XB @ W_upd + b) ----------------
__launch_bounds__(256, 5)
__global__ void k_gemmB(const unsigned short* __restrict__ XB,
                        const unsigned short* __restrict__ WTg, const void* __restrict__ Bp,
                        unsigned short* __restrict__ HoutBf, float* __restrict__ HoutF,
                        const int* __restrict__ flags, int last) {
    __shared__ __align__(16) unsigned short sWT[DD * DD];  // 32 KB
    const int tid  = threadIdx.x;
    const int wave = tid >> 6;
    const int lane = tid & 63;
    const int f32  = flags[0];
    const int m    = lane & 15;
    const int quad = lane >> 4;
    const int rowbase = blockIdx.x * RB + wave * 16;
    const int row  = rowbase + m;

    stage_w((const uintv4*)WTg, (uintv4*)sWT, tid);

    bfrag af[4];
    const uintv4* Xv = (const uintv4*)XB;
#pragma unroll
    for (int ks = 0; ks < 4; ks++) {
        const int k0 = ks * 32 + quad * 8;
        frag_cast fc;
        fc.u4 = __builtin_nontemporal_load(&Xv[row * 16 + (k0 >> 3)]);  // single-use stream
        af[ks] = fc.b;
    }
    __syncthreads();

    ffrag acc[8];
#pragma unroll
    for (int i = 0; i < 8; i++) acc[i] = (ffrag)(0.0f);
    mfma_rows(af, (const bfrag*)sWT, m, quad, acc);

#pragma unroll
    for (int ct = 0; ct < 8; ct++) {
        int col = ct * 16 + m;
        float bb = ld_in(Bp, col, f32);
#pragma unroll
        for (int reg = 0; reg < 4; reg++) {
            int orow = rowbase + quad * 4 + reg;
            if (orow < NN) {
                float s = 1.0f / (1.0f + __expf(-(acc[ct][reg] + bb)));
                if (!last) {
                    st_h2(HoutBf, ct, m, orow, s);
                } else if (f32) {
                    HoutF[orow * DD + col] = s;
                } else {
                    ((unsigned short*)HoutF)[orow * DD + col] = (unsigned short)f2bfbits(s);
                }
            }
        }
    }
}

extern "C" void kernel_launch(void* const* d_in, const int* in_sizes, int n_in,
                              void* d_out, int out_size, void* d_ws, size_t ws_size,
                              hipStream_t stream) {
    const void* X  = d_in[0];
    const void* We = d_in[1];
    const void* be = d_in[2];
    const void* Wu = d_in[3];
    const void* bu = d_in[4];
    const int* adj = (const int*)d_in[5];

    // ws layout = R12 (~17.2 MB, <26 MB proven). REC overlays HW.
    char* p = (char*)d_ws;
    int* FLAGS = (int*)p;                       p += 256;
    int* ROWS  = (int*)p;                       p += ((NN + 1) * 4 + 252) / 256 * 256;
    int* SUMS  = (int*)p;                       p += 256;
    int* BHIST = (int*)p;                       p += ((SB * 256 * 4 + 255) / 256) * 256;
    int* BOFF  = (int*)p;                       p += ((SB * 256 * 4 + 255) / 256) * 256;
    int* BBASE = (int*)p;                       p += 1024;
    int* ORDER = (int*)p;                       p += ((NN * 4 + 255) / 256) * 256;
    int* DEG   = (int*)p;                       p += ((NN * 4 + 255) / 256) * 256;
    int* DEGLO = (int*)p;                       p += ((NN * 4 + 255) / 256) * 256;
    unsigned short* NBR = (unsigned short*)p;   p += (size_t)2 * NE * 2;
    unsigned short* WeT = (unsigned short*)p;   p += DD * DD * 2;
    unsigned short* WuT = (unsigned short*)p;   p += DD * DD * 2;
    int* BH1   = (int*)p;                       p += ((NBUCK * NBE * 4 + 255) / 256) * 256;
    int* BKOFF = (int*)p;                       p += ((NBUCK * NBE * 4 + 255) / 256) * 256;
    int* BKBASE = (int*)p;                      p += 1024;
    unsigned short* HW  = (unsigned short*)p;   // 12.8 MB + slack (gemmB over-read)
    unsigned* REC = (unsigned*)p;               // overlays HW[0 .. 4.8M)

    // h planes live in d_out's upper half (bytes 12.8M..25.6M); dead before the
    // final row-major f32 write (gather consumes them first, stream-ordered).
    unsigned short* HA = (unsigned short*)d_out + (size_t)NN * DD;

    k_prep<<<DD + 1, 256, 0, stream>>>((const unsigned*)We, (const unsigned*)adj,
                                       We, Wu, WeT, WuT, FLAGS);
    k_main1<<<GB + NBE, 256, 0, stream>>>(X, WeT, be, HA, FLAGS, adj, BH1);
    k_scanB<<<1, 1024, 0, stream>>>(BH1, BKOFF, BKBASE);
    k_p1b<<<NBE, 256, 0, stream>>>(adj, FLAGS, BKBASE, BKOFF, REC);
    k_p2a<<<NBUCK, 256, 0, stream>>>(REC, BKBASE, DEG, DEGLO);
    k_scan1<<<SB, 1024, 0, stream>>>(DEG, ROWS, SUMS, BHIST);
    k_scan2<<<1, 256, 0, stream>>>(SUMS, SB, BHIST, BOFF, BBASE);
    k_scan3<<<SB, 1024, 0, stream>>>(SUMS, ROWS, DEG, BOFF, BBASE, ORDER);
    k_p2b<<<NBUCK, 256, 0, stream>>>(REC, BKBASE, ROWS, DEGLO, NBR);

    for (int it = 0; it < 3; ++it) {
        int last = (it == 2);
        k_gathL<<<GQB3, 256, 0, stream>>>((const unsigned*)HA, ROWS, DEGLO, NBR, ORDER,
                                          (unsigned*)HW);
        k_gathH<<<GQB3, 256, 0, stream>>>((const unsigned*)HA, ROWS, DEGLO, NBR, ORDER,
                                          (unsigned*)HW);
        k_gemmB<<<GB, 256, 0, stream>>>(HW, WuT, bu, HA, (float*)d_out, FLAGS, last);
    }
}

// Round 14
// 326.755 us; speedup vs baseline: 1.1081x; 1.1081x over previous
//
#include <hip/hip_runtime.h>
#include <hip/hip_bf16.h>

#define NN 50000
#define NE 600000
#define DD 128
#define RB 64            // rows per MFMA block (4 waves x 16 rows)
#define GB ((NN + RB - 1) / RB)      // 782 MFMA blocks
#define NBE ((NE + 4095) / 4096)     // 147 edge blocks (16 edges/thread)
#define NBUCK 196                    // node buckets of 256 (node>>8); = 4*SB exactly
#define SB ((NN + 1023) / 1024)      // 49 scan blocks
#define GQB3 (2 * ((NN + 31) / 32))  // 3126 gather blocks (2 planes x 1563 chunks)

typedef __bf16 bfrag __attribute__((ext_vector_type(8)));
typedef float  ffrag __attribute__((ext_vector_type(4)));
typedef unsigned uintv4 __attribute__((ext_vector_type(4)));   // native vec for nontemporal
typedef unsigned uintv2 __attribute__((ext_vector_type(2)));

union frag_cast { uintv4 u4; unsigned u[4]; bfrag b; };

__device__ __forceinline__ float bfbits2f(unsigned v) { return __uint_as_float(v << 16); }
__device__ __forceinline__ unsigned f2bfbits(float f) {
    unsigned u = __float_as_uint(f);
    return (u + 0x7FFFu + ((u >> 16) & 1u)) >> 16;   // RNE
}

__device__ __forceinline__ float ld_in(const void* p, int idx, int f32) {
    return f32 ? ((const float*)p)[idx]
               : bfbits2f(((const unsigned short*)p)[idx]);
}

__device__ __forceinline__ void ld_edge_nt(const int* adj, int e, int i64, int& s, int& d) {
    if (i64) {
        s = __builtin_nontemporal_load(&adj[4 * e]);
        d = __builtin_nontemporal_load(&adj[4 * e + 2]);
    } else {
        s = __builtin_nontemporal_load(&adj[2 * e]);
        d = __builtin_nontemporal_load(&adj[2 * e + 1]);
    }
}

// ---------------- prep: weight transpose + sniff ----------------
__global__ void k_prep(const unsigned* __restrict__ Ww, const unsigned* __restrict__ adjw,
                       const void* __restrict__ We, const void* __restrict__ Wu,
                       unsigned short* __restrict__ WeT, unsigned short* __restrict__ WuT,
                       int* __restrict__ flags) {
    const int tid = threadIdx.x;
    if (blockIdx.x < DD) {
        __shared__ int scnt;
        if (tid == 0) scnt = 0;
        __syncthreads();
        int c = 0;
        for (int i = tid; i < 512; i += 256) {
            unsigned e = (Ww[i] >> 7) & 0xFFu;
            c += (e >= 0x60u && e <= 0x85u) ? 1 : 0;   // plausible low-half bf16?
        }
        atomicAdd(&scnt, c);
        __syncthreads();
        const int f32 = (scnt >= 256) ? 0 : 1;
        const int k = blockIdx.x;
        if (tid < DD) {
            WeT[tid * DD + k] = (unsigned short)f2bfbits(ld_in(We, k * DD + tid, f32));
        } else {
            int n = tid - DD;
            WuT[n * DD + k] = (unsigned short)f2bfbits(ld_in(Wu, k * DD + n, f32));
        }
        return;
    }
    __shared__ int cnt[2];
    if (tid < 2) cnt[tid] = 0;
    __syncthreads();
    int c0 = 0, c1 = 0;
    for (int i = tid; i < 512; i += 256) {
        unsigned e = (Ww[i] >> 7) & 0xFFu;
        c0 += (e >= 0x60u && e <= 0x85u) ? 1 : 0;
        c1 += (adjw[2 * i + 1] == 0u) ? 1 : 0;          // int64 zero high words?
    }
    atomicAdd(&cnt[0], c0);
    atomicAdd(&cnt[1], c1);
    __syncthreads();
    if (tid == 0) {
        flags[0] = (cnt[0] >= 256) ? 0 : 1;   // fp32 inputs?
        flags[1] = (cnt[1] >= 256) ? 1 : 0;   // int64 adjacency?
    }
}

// ---------------- W staging: fragment-major LDS, INVERSE permutation ----------------
__device__ __forceinline__ void stage_w(const uintv4* __restrict__ WTg, uintv4* sW, int tid) {
#pragma unroll
    for (int k = 0; k < 8; k++) {
        int d = k * 256 + tid;
        int m = d & 15, rest = d >> 4;
        int quad = rest & 3, ks = (rest >> 2) & 3, ct = rest >> 4;
        sW[d] = WTg[(ct * 16 + m) * 16 + (ks * 4 + quad)];
    }
}

// ---------------- MFMA core: A from registers, B fragment-major from LDS ----------
__device__ __forceinline__ void mfma_rows(const bfrag af[4], const bfrag* sW,
                                          int m, int quad, ffrag acc[8]) {
#pragma unroll
    for (int ks = 0; ks < 4; ks++) {
#pragma unroll
        for (int ct = 0; ct < 8; ct++) {
            bfrag bf_ = sW[((ct * 4 + ks) * 4 + quad) * 16 + m];
            acc[ct] = __builtin_amdgcn_mfma_f32_16x16x32_bf16(af[ks], bf_, acc[ct], 0, 0, 0);
        }
    }
}

// H layout between GEMMs: 2 HALF-ROW PLANES H2[plane][node][64cols] (128B/node/plane)
// -> every gather neighbor-read is ONE fully-used 128B L2 line request.
__device__ __forceinline__ void st_h2(unsigned short* __restrict__ Hout,
                                      int ct, int m, int orow, float z) {
    Hout[(size_t)(ct >> 2) * (NN * 64) + (size_t)orow * 64 + (ct & 3) * 16 + m] =
        (unsigned short)f2bfbits(z);
}

// ---------------- fused: emb GEMM (blocks < GB) || P1a bucket histogram (rest) -----
__launch_bounds__(256, 5)
__global__ void k_main1(const void* __restrict__ Xp, const unsigned short* __restrict__ WTg,
                        const void* __restrict__ Bp, unsigned short* __restrict__ Hout,
                        const int* __restrict__ flags, const int* __restrict__ adj,
                        int* __restrict__ bh1) {
    __shared__ __align__(16) unsigned short sWT[DD * DD];  // 32 KB
    const int tid = threadIdx.x;
    if (blockIdx.x >= GB) {
        int* hist = (int*)sWT;                 // reuse LDS (edge blocks never stage W)
        const int bb = blockIdx.x - GB;
        hist[tid] = 0;
        __syncthreads();
        const int i64 = flags[1];
#pragma unroll
        for (int k = 0; k < 16; k++) {
            const int e = bb * 4096 + k * 256 + tid;
            if (e < NE) {
                int s, d;
                ld_edge_nt(adj, e, i64, s, d);
                if ((unsigned)s < NN && (unsigned)d < NN) {
                    atomicAdd(&hist[s >> 8], 1);   // LDS atomic (~21/bucket avg)
                    atomicAdd(&hist[d >> 8], 1);
                }
            }
        }
        __syncthreads();
        if (tid < NBUCK) bh1[tid * NBE + bb] = hist[tid];
        return;
    }
    // -------- emb path: h0 = relu(X @ W_emb + b) -> bf16 half-row planes --------
    const int wave = tid >> 6;
    const int lane = tid & 63;
    const int f32  = flags[0];
    const int m    = lane & 15;
    const int quad = lane >> 4;
    const int rowbase = blockIdx.x * RB + wave * 16;
    const int row  = rowbase + m;
    const int rc   = (row < NN) ? row : (NN - 1);   // clamp for load; stores guarded

    stage_w((const uintv4*)WTg, (uintv4*)sWT, tid);

    bfrag af[4];
    if (f32) {
        const float4* Xf = (const float4*)Xp;
#pragma unroll
        for (int ks = 0; ks < 4; ks++) {
            const int k0 = ks * 32 + quad * 8;
            float4 a0 = Xf[rc * 32 + (k0 >> 2)];
            float4 a1 = Xf[rc * 32 + (k0 >> 2) + 1];
            frag_cast fc;
            fc.u[0] = f2bfbits(a0.x) | (f2bfbits(a0.y) << 16);
            fc.u[1] = f2bfbits(a0.z) | (f2bfbits(a0.w) << 16);
            fc.u[2] = f2bfbits(a1.x) | (f2bfbits(a1.y) << 16);
            fc.u[3] = f2bfbits(a1.z) | (f2bfbits(a1.w) << 16);
            af[ks] = fc.b;
        }
    } else {
        const uintv4* Xv = (const uintv4*)Xp;
#pragma unroll
        for (int ks = 0; ks < 4; ks++) {
            const int k0 = ks * 32 + quad * 8;
            frag_cast fc;
            fc.u4 = Xv[rc * 16 + (k0 >> 3)];
            af[ks] = fc.b;
        }
    }
    __syncthreads();

    ffrag acc[8];
#pragma unroll
    for (int i = 0; i < 8; i++) acc[i] = (ffrag)(0.0f);
    mfma_rows(af, (const bfrag*)sWT, m, quad, acc);

#pragma unroll
    for (int ct = 0; ct < 8; ct++) {
        int col = ct * 16 + m;
        float bb = ld_in(Bp, col, f32);
#pragma unroll
        for (int reg = 0; reg < 4; reg++) {
            int orow = rowbase + quad * 4 + reg;
            if (orow < NN) {
                float z = fmaxf(acc[ct][reg] + bb, 0.0f);
                st_h2(Hout, ct, m, orow, z);
            }
        }
    }
}

// ---------------- scanB: per-bucket scan across edge blocks + bucket bases ---------
__global__ void k_scanB(const int* __restrict__ bh1, int* __restrict__ bkoff,
                        int* __restrict__ bkbase) {
    __shared__ int tot[256];
    __shared__ int wps[4];
    const int t = threadIdx.x, lane = t & 63, w = t >> 6;   // 16 waves
    for (int k = w; k < NBUCK; k += 16) {
        int vals[3];                                        // ceil(147/64)=3 chunks
#pragma unroll
        for (int c = 0; c < 3; c++) {
            int idx = c * 64 + lane;
            vals[c] = (idx < NBE) ? bh1[k * NBE + idx] : 0;
        }
        int carry = 0;
#pragma unroll
        for (int c = 0; c < 3; c++) {
            int v = vals[c], x = v;
#pragma unroll
            for (int off = 1; off < 64; off <<= 1) {
                int y = __shfl_up(x, off, 64);
                if (lane >= off) x += y;
            }
            int idx = c * 64 + lane;
            if (idx < NBE) bkoff[k * NBE + idx] = carry + x - v;
            carry += __shfl(x, 63, 64);
        }
        if (lane == 0) tot[k] = carry;
    }
    if (t < 256 && t >= NBUCK) tot[t] = 0;
    __syncthreads();
    int v = 0, x = 0;
    if (t < 256) {
        v = tot[t]; x = v;
#pragma unroll
        for (int off = 1; off < 64; off <<= 1) {
            int y = __shfl_up(x, off, 64);
            if (lane >= off) x += y;
        }
        if (lane == 63) wps[w] = x;
    }
    __syncthreads();
    if (t < NBUCK) {
        int add = 0;
        for (int k = 0; k < w; k++) add += wps[k];
        bkbase[t] = x - v + add;
        if (t == NBUCK - 1) bkbase[NBUCK] = x + add;   // total endpoint count
    }
}

// ---------------- p1b: bucket-sorted record scatter (LDS cursors, no global atomics)
__launch_bounds__(256)
__global__ void k_p1b(const int* __restrict__ adj, const int* __restrict__ flags,
                      const int* __restrict__ bkbase, const int* __restrict__ bkoff,
                      unsigned* __restrict__ rec) {
    __shared__ int cur[256];
    const int tid = threadIdx.x;
    const int bb = blockIdx.x;
    if (tid < NBUCK) cur[tid] = bkbase[tid] + bkoff[tid * NBE + bb];
    __syncthreads();
    const int i64 = flags[1];
#pragma unroll
    for (int k = 0; k < 16; k++) {
        const int e = bb * 4096 + k * 256 + tid;
        if (e < NE) {
            int s, d;
            ld_edge_nt(adj, e, i64, s, d);
            if ((unsigned)s < NN && (unsigned)d < NN) {   // same predicate as P1a
                int ps = atomicAdd(&cur[s >> 8], 1);      // LDS atomic
                rec[ps] = (unsigned)s | ((unsigned)d << 16);
                int pd = atomicAdd(&cur[d >> 8], 1);
                rec[pd] = (unsigned)d | ((unsigned)s << 16);
            }
        }
    }
}

// ---------------- scan1 (p2a FUSED): degree from REC + prefix + sort histogram -----
// Block b covers nodes [1024b,1024b+1024) == buckets [4b,4b+4) exactly (NBUCK=4*SB).
// Records are bucket-sorted, so the block's degree histogram reads one contiguous
// REC range - deletes the separate k_p2a dispatch and its DEG round-trip leg.
__global__ void k_scan1(const unsigned* __restrict__ rec, const int* __restrict__ bkbase,
                        int* __restrict__ deg, int* __restrict__ rows,
                        int* __restrict__ sums, int* __restrict__ bhist) {
    __shared__ int wsum[16];
    __shared__ int woff[16];
    __shared__ int hist[256];
    __shared__ int dh[1024];
    const int tid  = threadIdx.x;
    const int wid  = tid >> 6;
    const int lane = tid & 63;
    const int i = blockIdx.x * 1024 + tid;
    if (tid < 256) hist[tid] = 0;
    dh[tid] = 0;
    __syncthreads();
    const int st = bkbase[blockIdx.x * 4];
    const int en = bkbase[blockIdx.x * 4 + 4];
    const int nbase = blockIdx.x * 1024;
    for (int j = st + tid; j < en; j += 1024)
        atomicAdd(&dh[(int)(rec[j] & 0xFFFFu) - nbase], 1);   // LDS atomic
    __syncthreads();
    int x = (i < NN) ? dh[tid] : 0;
    if (i < NN) {
        deg[i] = x;                                           // scan3 needs it
        atomicAdd(&hist[(x < 255) ? x : 255], 1);             // LDS atomic
    }
#pragma unroll
    for (int off = 1; off < 64; off <<= 1) {
        int y = __shfl_up(x, off, 64);
        if (lane >= off) x += y;
    }
    if (lane == 63) wsum[wid] = x;
    __syncthreads();
    if (wid == 0) {
        int s  = (lane < 16) ? wsum[lane] : 0;
        int xs = s;
#pragma unroll
        for (int off = 1; off < 16; off <<= 1) {
            int y = __shfl_up(xs, off, 64);
            if (lane >= off) xs += y;
        }
        if (lane < 16) woff[lane] = xs - s;
        if (lane == 15) sums[blockIdx.x] = xs;
    }
    __syncthreads();
    if (i < NN) rows[i + 1] = x + woff[wid];
    if (tid < 256) bhist[blockIdx.x * 256 + tid] = hist[tid];
}

// ---------------- scan2: block-sums scan + counting-sort offset tables ------------
__global__ void k_scan2(int* __restrict__ sums, int nb,
                        const int* __restrict__ bhist, int* __restrict__ boff,
                        int* __restrict__ bbase) {
    __shared__ int wps[4];
    const int t = threadIdx.x, lane = t & 63, w = t >> 6;
    if (w == 0) {
        int v = (lane < nb) ? sums[lane] : 0;
        int x = v;
        for (int off = 1; off < 64; off <<= 1) {
            int y = __shfl_up(x, off, 64);
            if (lane >= off) x += y;
        }
        if (lane < nb) sums[lane] = x - v;   // exclusive
    }
    int run = 0;
    for (int blk = 0; blk < nb; blk++) {
        int c = bhist[blk * 256 + t];
        boff[blk * 256 + t] = run;
        run += c;
    }
    int v = run, x = v;
    for (int off = 1; off < 64; off <<= 1) {
        int y = __shfl_up(x, off, 64);
        if (lane >= off) x += y;
    }
    if (lane == 63) wps[w] = x;
    __syncthreads();
    int add = 0;
    for (int k = 0; k < w; k++) add += wps[k];
    bbase[t] = x - v + add;                  // exclusive over 256 bins
}

// ---------------- scan3: finalize rows + contention-free sort scatter -------------
__global__ void k_scan3(const int* __restrict__ sums, int* __restrict__ rows,
                        const int* __restrict__ deg, const int* __restrict__ boff,
                        const int* __restrict__ bbase, int* __restrict__ order) {
    __shared__ int lh[256];
    const int tid = threadIdx.x;
    if (tid < 256) lh[tid] = 0;
    __syncthreads();
    int i = blockIdx.x * 1024 + tid;
    int d = 0, r = 0;
    if (i < NN) {
        rows[i + 1] += sums[blockIdx.x];
        if (i == 0) rows[0] = 0;
        d = deg[i];
        d = (d < 255) ? d : 255;
        r = atomicAdd(&lh[d], 1);            // LDS atomic
        order[bbase[d] + boff[blockIdx.x * 256 + d] + r] = i;  // perf hint only
    }
}

// ---------------- p2b: per-bucket NBR fill via rows[] + LDS cursors ---------------
__launch_bounds__(256)
__global__ void k_p2b(const unsigned* __restrict__ rec, const int* __restrict__ bkbase,
                      const int* __restrict__ rows, unsigned short* __restrict__ nbr) {
    __shared__ int lcur[256];
    const int tid = threadIdx.x;
    const int k = blockIdx.x;
    const int node = k * 256 + tid;
    lcur[tid] = (node < NN) ? rows[node] : 0;
    __syncthreads();
    const int st = bkbase[k], en = bkbase[k + 1];
    for (int j = st + tid; j < en; j += 256) {
        unsigned r = rec[j];
        int slot = atomicAdd(&lcur[r & 255], 1);          // LDS atomic
        nbr[slot] = (unsigned short)(r >> 16);
    }
}

__device__ __forceinline__ void accv4(float a[8], uintv4 v) {
#pragma unroll
    for (int k = 0; k < 4; k++) {
        a[2 * k]     += bfbits2f(v[k] & 0xFFFFu);
        a[2 * k + 1] += bfbits2f(v[k] >> 16);
    }
}

// ---------------- degree-sorted full-line gather (R10 champion version) ------------
// Compulsory-miss-bound: 8 XCDs x 6.4 MB plane = 51.2 MB/iter minimum FETCH at
// ~1.55 TB/s random-line fabric; measured 68.9 MB (R12). All alternative layouts
// mapped and worse: 64B requests (R11), 32B (R3/R4), implicit/explicit phase
// splits (R12/R13). This is the floor for this algorithm.
__launch_bounds__(256)
__global__ void k_gath5(const unsigned* __restrict__ Hp, const int* __restrict__ rows,
                        const unsigned short* __restrict__ nbr,
                        const int* __restrict__ order, unsigned* __restrict__ XB32) {
    const int plane = blockIdx.x & 1;
    const int chunk = blockIdx.x >> 1;
    const int g     = threadIdx.x >> 3;                // 0..31 node-groups per block
    const int l8    = threadIdx.x & 7;
    const int opos  = chunk * 32 + g;
    const int nid   = order[(opos < NN) ? opos : (NN - 1)];
    const uintv4* Pv = (const uintv4*)Hp + (size_t)plane * (NN * 8);
    const int st = rows[nid], en = rows[nid + 1];
    uintv4 sv = Pv[(size_t)nid * 8 + l8];              // self term
    float a[8];
#pragma unroll
    for (int k = 0; k < 4; k++) {
        a[2 * k]     = bfbits2f(sv[k] & 0xFFFFu);
        a[2 * k + 1] = bfbits2f(sv[k] >> 16);
    }
    int j = st;
    for (; j + 8 <= en; j += 8) {                      // 8 line-loads in flight/group
        int n[8];
#pragma unroll
        for (int t = 0; t < 8; t++) n[t] = nbr[j + t];
        uintv4 v[8];
#pragma unroll
        for (int t = 0; t < 8; t++) v[t] = Pv[(size_t)n[t] * 8 + l8];
#pragma unroll
        for (int t = 0; t < 8; t++) accv4(a, v[t]);
    }
    for (; j < en; ++j) accv4(a, Pv[(size_t)nbr[j] * 8 + l8]);
    const float inv = 1.0f / (float)(en - st + 1);
    if (opos < NN) {
        uintv4 pk;
#pragma unroll
        for (int k = 0; k < 4; k++)
            pk[k] = f2bfbits(a[2 * k] * inv) | (f2bfbits(a[2 * k + 1] * inv) << 16);
        // dwords [plane*32 .. +32) of row nid -> assembles row-major XB
        __builtin_nontemporal_store(pk, (uintv4*)XB32 + (size_t)nid * 16 + plane * 8 + l8);
    }
}

// ---------------- GEMM 2: h_new = sigmoid(XB @ W_upd + b) ----------------
__launch_bounds__(256, 5)
__global__ void k_gemmB(const unsigned short* __restrict__ XB,
                        const unsigned short* __restrict__ WTg, const void* __restrict__ Bp,
                        unsigned short* __restrict__ HoutBf, float* __restrict__ HoutF,
                        const int* __restrict__ flags, int last) {
    __shared__ __align__(16) unsigned short sWT[DD * DD];  // 32 KB
    const int tid  = threadIdx.x;
    const int wave = tid >> 6;
    const int lane = tid & 63;
    const int f32  = flags[0];
    const int m    = lane & 15;
    const int quad = lane >> 4;
    const int rowbase = blockIdx.x * RB + wave * 16;
    const int row  = rowbase + m;

    stage_w((const uintv4*)WTg, (uintv4*)sWT, tid);

    bfrag af[4];
    const uintv4* Xv = (const uintv4*)XB;
#pragma unroll
    for (int ks = 0; ks < 4; ks++) {
        const int k0 = ks * 32 + quad * 8;
        frag_cast fc;
        fc.u4 = __builtin_nontemporal_load(&Xv[row * 16 + (k0 >> 3)]);  // single-use stream
        af[ks] = fc.b;
    }
    __syncthreads();

    ffrag acc[8];
#pragma unroll
    for (int i = 0; i < 8; i++) acc[i] = (ffrag)(0.0f);
    mfma_rows(af, (const bfrag*)sWT, m, quad, acc);

#pragma unroll
    for (int ct = 0; ct < 8; ct++) {
        int col = ct * 16 + m;
        float bb = ld_in(Bp, col, f32);
#pragma unroll
        for (int reg = 0; reg < 4; reg++) {
            int orow = rowbase + quad * 4 + reg;
            if (orow < NN) {
                float s = 1.0f / (1.0f + __expf(-(acc[ct][reg] + bb)));
                if (!last) {
                    st_h2(HoutBf, ct, m, orow, s);
                } else if (f32) {
                    HoutF[orow * DD + col] = s;
                } else {
                    ((unsigned short*)HoutF)[orow * DD + col] = (unsigned short)f2bfbits(s);
                }
            }
        }
    }
}

extern "C" void kernel_launch(void* const* d_in, const int* in_sizes, int n_in,
                              void* d_out, int out_size, void* d_ws, size_t ws_size,
                              hipStream_t stream) {
    const void* X  = d_in[0];
    const void* We = d_in[1];
    const void* be = d_in[2];
    const void* Wu = d_in[3];
    const void* bu = d_in[4];
    const int* adj = (const int*)d_in[5];

    // ws layout = R10 (~17 MB, <26 MB proven). REC overlays HW.
    char* p = (char*)d_ws;
    int* FLAGS = (int*)p;                       p += 256;
    int* ROWS  = (int*)p;                       p += ((NN + 1) * 4 + 252) / 256 * 256;
    int* SUMS  = (int*)p;                       p += 256;
    int* BHIST = (int*)p;                       p += ((SB * 256 * 4 + 255) / 256) * 256;
    int* BOFF  = (int*)p;                       p += ((SB * 256 * 4 + 255) / 256) * 256;
    int* BBASE = (int*)p;                       p += 1024;
    int* ORDER = (int*)p;                       p += ((NN * 4 + 255) / 256) * 256;
    int* DEG   = (int*)p;                       p += ((NN * 4 + 255) / 256) * 256;
    unsigned short* NBR = (unsigned short*)p;   p += (size_t)2 * NE * 2;
    unsigned short* WeT = (unsigned short*)p;   p += DD * DD * 2;
    unsigned short* WuT = (unsigned short*)p;   p += DD * DD * 2;
    int* BH1   = (int*)p;                       p += ((NBUCK * NBE * 4 + 255) / 256) * 256;
    int* BKOFF = (int*)p;                       p += ((NBUCK * NBE * 4 + 255) / 256) * 256;
    int* BKBASE = (int*)p;                      p += 1024;
    unsigned short* HW  = (unsigned short*)p;   // 12.8 MB + slack (gemmB over-read)
    unsigned* REC = (unsigned*)p;               // overlays HW[0 .. 4.8M)

    // h planes live in d_out's upper half (bytes 12.8M..25.6M); dead before the
    // final row-major f32 write (gather consumes them first, stream-ordered).
    unsigned short* HA = (unsigned short*)d_out + (size_t)NN * DD;

    k_prep<<<DD + 1, 256, 0, stream>>>((const unsigned*)We, (const unsigned*)adj,
                                       We, Wu, WeT, WuT, FLAGS);
    k_main1<<<GB + NBE, 256, 0, stream>>>(X, WeT, be, HA, FLAGS, adj, BH1);
    k_scanB<<<1, 1024, 0, stream>>>(BH1, BKOFF, BKBASE);
    k_p1b<<<NBE, 256, 0, stream>>>(adj, FLAGS, BKBASE, BKOFF, REC);
    k_scan1<<<SB, 1024, 0, stream>>>(REC, BKBASE, DEG, ROWS, SUMS, BHIST);
    k_scan2<<<1, 256, 0, stream>>>(SUMS, SB, BHIST, BOFF, BBASE);
    k_scan3<<<SB, 1024, 0, stream>>>(SUMS, ROWS, DEG, BOFF, BBASE, ORDER);
    k_p2b<<<NBUCK, 256, 0, stream>>>(REC, BKBASE, ROWS, NBR);

    for (int it = 0; it < 3; ++it) {
        int last = (it == 2);
        k_gath5<<<GQB3, 256, 0, stream>>>((const unsigned*)HA, ROWS, NBR, ORDER, (unsigned*)HW);
        k_gemmB<<<GB, 256, 0, stream>>>(HW, WuT, bu, HA, (float*)d_out, FLAGS, last);
    }
}